// Round 5
// baseline (559.851 us; speedup 1.0000x reference)
//
#include <hip/hip_runtime.h>
#include <hip/hip_cooperative_groups.h>
#include <hip/hip_bf16.h>

namespace cg = cooperative_groups;

#define N_NODES 8192
#define E_EDGES 262144
#define IN_DIM  512
#define HID_DIM 256
#define Z_DIM   64

typedef float f32x4  __attribute__((ext_vector_type(4)));
typedef float f32x16 __attribute__((ext_vector_type(16)));
typedef short s16x4  __attribute__((ext_vector_type(4)));
typedef short s16x8  __attribute__((ext_vector_type(8)));

static __device__ __forceinline__ short bf16_bits(float f) {
    __hip_bfloat16 b = __float2bfloat16(f);
    return *reinterpret_cast<short*>(&b);
}
static __device__ __forceinline__ float bits_to_f32(short s) {
    __hip_bfloat16 b = *reinterpret_cast<__hip_bfloat16*>(&s);
    return __bfloat162float(b);
}

static __device__ __forceinline__ void gload_lds16(const void* g, void* l) {
    __builtin_amdgcn_global_load_lds((const __attribute__((address_space(1))) void*)g,
                                     (__attribute__((address_space(3))) void*)l, 16, 0, 0);
}

// ================================================================ MEGA KERNEL
// Grid 256 x 512 threads (1 block/CU, 8 waves), cooperative launch.
// Phases separated by grid.sync(); all per-element arithmetic chains are
// bit-identical to the verified 5-kernel version.
__global__ __launch_bounds__(512) void gcn_mega(
        const float* __restrict__ x, const float* __restrict__ w1,
        const float* __restrict__ w2,
        const int* __restrict__ edge_row, const int* __restrict__ edge_col,
        const float* __restrict__ edge_weight,
        short* __restrict__ xhi, short* __restrict__ xlo,
        short* __restrict__ w1t_hi, short* __restrict__ w1t_lo,
        float* __restrict__ support, float* __restrict__ zpre,
        __hip_bfloat16* __restrict__ zb, int* __restrict__ row_ptr,
        float* __restrict__ z_out, float* __restrict__ recon) {
    __shared__ __align__(16) char smem[49152];     // gemm1: A(32K)+B(16K); spmm: hrow overlay
    cg::grid_group grid = cg::this_grid();

    const int tid  = threadIdx.x;
    const int bid  = blockIdx.x;
    const int gtid = bid * 512 + tid;              // 0 .. 131071
    const int wave = tid >> 6, lane = tid & 63;

    // ---------------- phase 1: prep (split x, transpose-split w1, rowptr) ----
    {
        // split_x: 1,048,576 f32x4 groups, 8 per thread, coalesced
        #pragma unroll
        for (int j = 0; j < 8; j++) {
            size_t gid = (size_t)gtid + (size_t)131072 * j;
            f32x4 v = *(const f32x4*)(x + gid * 4);
            s16x4 h, l;
            #pragma unroll
            for (int q = 0; q < 4; q++) {
                short hb = bf16_bits(v[q]);
                h[q] = hb;
                l[q] = bf16_bits(v[q] - bits_to_f32(hb));
            }
            *(s16x4*)(xhi + gid * 4) = h;
            *(s16x4*)(xlo + gid * 4) = l;
        }
        // w1[512][256] -> w1t[256][512] hi/lo: exactly one element per thread
        {
            int k = gtid / HID_DIM, n = gtid % HID_DIM;
            float v = w1[gtid];
            short hb = bf16_bits(v);
            w1t_hi[(size_t)n * IN_DIM + k] = hb;
            w1t_lo[(size_t)n * IN_DIM + k] = bf16_bits(v - bits_to_f32(hb));
        }
        // rowptr via binary search on sorted edge_row
        if (gtid <= N_NODES) {
            int lo = 0, hi = E_EDGES;
            while (lo < hi) {
                int mid = (lo + hi) >> 1;
                if (edge_row[mid] < gtid) lo = mid + 1; else hi = mid;
            }
            row_ptr[gtid] = lo;
        }
    }
    grid.sync();

    // ---------------- phase 2: gemm1 support = x @ w1 (split-bf16 MFMA) ------
    // Block tile 128x64, BK=64, 8 waves 4x2; identical K-order to verified ver.
    {
        short* lA0 = (short*)smem;                 // Ah [128*64]
        short* lA1 = (short*)(smem + 16384);       // Al
        short* lB0 = (short*)(smem + 32768);       // Bh [64*64]
        short* lB1 = (short*)(smem + 40960);       // Bl
        const int wr = wave >> 1, wc = wave & 1;
        const int R0 = (bid >> 2) * 128;
        const int C0 = (bid & 3) * 64;
        const int l31 = lane & 31, lhi = lane >> 5;

        const int rowA = 32 * wr + l31;
        const int rowB = 32 * wc + l31;
        const int baseA = rowA * 128 + 16 * lhi;
        const int baseB = rowB * 128 + 16 * lhi;
        const int swzA = (rowA & 7) << 4;
        const int swzB = (rowB & 7) << 4;

        f32x16 acc = 0.f;

        for (int k0 = 0; k0 < IN_DIM; k0 += 64) {
            #pragma unroll
            for (int j = 0; j < 2; j++) {
                int ch = tid + 512 * j;
                int r  = ch >> 3;
                int sc = (ch & 7) ^ (r & 7);
                size_t goff = (size_t)(R0 + r) * IN_DIM + k0 + sc * 8;
                gload_lds16(xhi + goff, lA0 + ch * 8);
                gload_lds16(xlo + goff, lA1 + ch * 8);
            }
            {
                int ch = tid;
                int r  = ch >> 3;
                int sc = (ch & 7) ^ (r & 7);
                size_t goff = (size_t)(C0 + r) * IN_DIM + k0 + sc * 8;
                gload_lds16(w1t_hi + goff, lB0 + ch * 8);
                gload_lds16(w1t_lo + goff, lB1 + ch * 8);
            }
            __syncthreads();

            #pragma unroll
            for (int kk = 0; kk < 4; kk++) {
                int boffA = (baseA + kk * 32) ^ swzA;
                int boffB = (baseB + kk * 32) ^ swzB;
                s16x8 ah = *(const s16x8*)((const char*)lA0 + boffA);
                s16x8 al = *(const s16x8*)((const char*)lA1 + boffA);
                s16x8 bh = *(const s16x8*)((const char*)lB0 + boffB);
                s16x8 bl = *(const s16x8*)((const char*)lB1 + boffB);
                acc = __builtin_amdgcn_mfma_f32_32x32x16_bf16(ah, bh, acc, 0, 0, 0);
                acc = __builtin_amdgcn_mfma_f32_32x32x16_bf16(al, bh, acc, 0, 0, 0);
                acc = __builtin_amdgcn_mfma_f32_32x32x16_bf16(ah, bl, acc, 0, 0, 0);
            }
            __syncthreads();
        }

        const int R = R0 + wr * 32, C = C0 + wc * 32;
        #pragma unroll
        for (int r = 0; r < 16; r++) {
            int m = (r & 3) + 8 * (r >> 2) + 4 * lhi;
            support[(size_t)(R + m) * HID_DIM + C + l31] = acc[r];
        }
    }
    grid.sync();

    // ---------------- phase 3: spmm1 + relu + h@W2 fused ---------------------
    // 32 rows per block, 4 per wave (sequential). Arithmetic chains identical
    // to the verified kernel (8-unroll = two nested 4-chains, same order).
    {
        f32x4 (*hrow)[64] = (f32x4(*)[64])smem;    // [8][64] overlay, wave-local
        const int d = lane * 4;
        for (int i4 = 0; i4 < 4; i4++) {
            const int row = bid * 32 + wave * 4 + i4;
            const int s = row_ptr[row], e = row_ptr[row + 1];
            f32x4 acc = 0.f;
            int i = s;
            for (; i + 8 <= e; i += 8) {
                int   c0 = edge_col[i],     c1 = edge_col[i + 1];
                int   c2 = edge_col[i + 2], c3 = edge_col[i + 3];
                int   c4 = edge_col[i + 4], c5 = edge_col[i + 5];
                int   c6 = edge_col[i + 6], c7 = edge_col[i + 7];
                float w0 = edge_weight[i],     w1v = edge_weight[i + 1];
                float w2v = edge_weight[i + 2], w3 = edge_weight[i + 3];
                float w4 = edge_weight[i + 4], w5 = edge_weight[i + 5];
                float w6 = edge_weight[i + 6], w7 = edge_weight[i + 7];
                f32x4 v0 = *(const f32x4*)(support + (size_t)c0 * HID_DIM + d);
                f32x4 v1 = *(const f32x4*)(support + (size_t)c1 * HID_DIM + d);
                f32x4 v2 = *(const f32x4*)(support + (size_t)c2 * HID_DIM + d);
                f32x4 v3 = *(const f32x4*)(support + (size_t)c3 * HID_DIM + d);
                f32x4 v4 = *(const f32x4*)(support + (size_t)c4 * HID_DIM + d);
                f32x4 v5 = *(const f32x4*)(support + (size_t)c5 * HID_DIM + d);
                f32x4 v6 = *(const f32x4*)(support + (size_t)c6 * HID_DIM + d);
                f32x4 v7 = *(const f32x4*)(support + (size_t)c7 * HID_DIM + d);
                #pragma unroll
                for (int j = 0; j < 4; j++) {
                    float t = fmaf(w0, v0[j], fmaf(w1v, v1[j], fmaf(w2v, v2[j], fmaf(w3, v3[j], acc[j]))));
                    acc[j]  = fmaf(w4, v4[j], fmaf(w5,  v5[j], fmaf(w6,  v6[j], fmaf(w7, v7[j], t))));
                }
            }
            for (; i + 4 <= e; i += 4) {
                int   c0 = edge_col[i],     c1 = edge_col[i + 1];
                int   c2 = edge_col[i + 2], c3 = edge_col[i + 3];
                float w0 = edge_weight[i],     w1v = edge_weight[i + 1];
                float w2v = edge_weight[i + 2], w3 = edge_weight[i + 3];
                f32x4 v0 = *(const f32x4*)(support + (size_t)c0 * HID_DIM + d);
                f32x4 v1 = *(const f32x4*)(support + (size_t)c1 * HID_DIM + d);
                f32x4 v2 = *(const f32x4*)(support + (size_t)c2 * HID_DIM + d);
                f32x4 v3 = *(const f32x4*)(support + (size_t)c3 * HID_DIM + d);
                #pragma unroll
                for (int j = 0; j < 4; j++)
                    acc[j] = fmaf(w0, v0[j], fmaf(w1v, v1[j], fmaf(w2v, v2[j], fmaf(w3, v3[j], acc[j]))));
            }
            for (; i < e; i++) {
                int   c = edge_col[i];
                float w = edge_weight[i];
                f32x4 v = *(const f32x4*)(support + (size_t)c * HID_DIM + d);
                #pragma unroll
                for (int j = 0; j < 4; j++) acc[j] = fmaf(w, v[j], acc[j]);
            }
            f32x4 r;
            #pragma unroll
            for (int j = 0; j < 4; j++) r[j] = fmaxf(acc[j], 0.f);
            hrow[wave][lane] = r;                    // wave-local LDS, in-order DS
            float z = 0.f;
            #pragma unroll 8
            for (int k4 = 0; k4 < HID_DIM / 4; k4++) {
                f32x4 h4 = hrow[wave][k4];           // broadcast read
                #pragma unroll
                for (int t = 0; t < 4; t++)
                    z = fmaf(h4[t], w2[(size_t)(k4 * 4 + t) * Z_DIM + lane], z);
            }
            zpre[(size_t)row * Z_DIM + lane] = z;
        }
    }
    grid.sync();

    // ---------------- phase 4: spmm2 -----------------------------------------
    {
        for (int i4 = 0; i4 < 4; i4++) {
            const int row = bid * 32 + wave * 4 + i4;
            const int s = row_ptr[row], e = row_ptr[row + 1];
            float acc = 0.f;
            int i = s;
            for (; i + 8 <= e; i += 8) {
                int   c0 = edge_col[i],     c1 = edge_col[i + 1];
                int   c2 = edge_col[i + 2], c3 = edge_col[i + 3];
                int   c4 = edge_col[i + 4], c5 = edge_col[i + 5];
                int   c6 = edge_col[i + 6], c7 = edge_col[i + 7];
                float w0 = edge_weight[i],     w1v = edge_weight[i + 1];
                float w2v = edge_weight[i + 2], w3 = edge_weight[i + 3];
                float w4 = edge_weight[i + 4], w5 = edge_weight[i + 5];
                float w6 = edge_weight[i + 6], w7 = edge_weight[i + 7];
                float v0 = zpre[(size_t)c0 * Z_DIM + lane];
                float v1 = zpre[(size_t)c1 * Z_DIM + lane];
                float v2 = zpre[(size_t)c2 * Z_DIM + lane];
                float v3 = zpre[(size_t)c3 * Z_DIM + lane];
                float v4 = zpre[(size_t)c4 * Z_DIM + lane];
                float v5 = zpre[(size_t)c5 * Z_DIM + lane];
                float v6 = zpre[(size_t)c6 * Z_DIM + lane];
                float v7 = zpre[(size_t)c7 * Z_DIM + lane];
                float t = fmaf(w0, v0, fmaf(w1v, v1, fmaf(w2v, v2, fmaf(w3, v3, acc))));
                acc     = fmaf(w4, v4, fmaf(w5,  v5, fmaf(w6,  v6, fmaf(w7, v7, t))));
            }
            for (; i + 4 <= e; i += 4) {
                int   c0 = edge_col[i],     c1 = edge_col[i + 1];
                int   c2 = edge_col[i + 2], c3 = edge_col[i + 3];
                float w0 = edge_weight[i],     w1v = edge_weight[i + 1];
                float w2v = edge_weight[i + 2], w3 = edge_weight[i + 3];
                float v0 = zpre[(size_t)c0 * Z_DIM + lane];
                float v1 = zpre[(size_t)c1 * Z_DIM + lane];
                float v2 = zpre[(size_t)c2 * Z_DIM + lane];
                float v3 = zpre[(size_t)c3 * Z_DIM + lane];
                acc = fmaf(w0, v0, fmaf(w1v, v1, fmaf(w2v, v2, fmaf(w3, v3, acc))));
            }
            for (; i < e; i++)
                acc = fmaf(edge_weight[i], zpre[(size_t)edge_col[i] * Z_DIM + lane], acc);
            z_out[(size_t)row * Z_DIM + lane] = acc;
            zb[(size_t)row * Z_DIM + lane]    = __float2bfloat16(acc);
        }
    }
    grid.sync();

    // ---------------- phase 5: recon = z @ z^T -------------------------------
    // 2048 tiles of 128x256; 8 per block; 8 waves in 2x4, each 64x64 (2x2 MFMA).
    {
        const int wr2 = wave >> 2, wc2 = wave & 3;
        const int l31 = lane & 31, lhi = lane >> 5;
        const short* zs = (const short*)zb;
        for (int t = 0; t < 8; t++) {
            int tile = bid * 8 + t;
            int ty = tile >> 5, tx = tile & 31;
            int R = ty * 128 + wr2 * 64;
            int C = tx * 256 + wc2 * 64;

            f32x16 acc[2][2];
            #pragma unroll
            for (int i = 0; i < 2; i++)
                #pragma unroll
                for (int j = 0; j < 2; j++) acc[i][j] = 0.f;

            #pragma unroll
            for (int s = 0; s < 4; s++) {
                s16x8 a[2], b[2];
                #pragma unroll
                for (int i = 0; i < 2; i++) {
                    a[i] = *(const s16x8*)(zs + (size_t)(R + i * 32 + l31) * Z_DIM + s * 16 + 8 * lhi);
                    b[i] = *(const s16x8*)(zs + (size_t)(C + i * 32 + l31) * Z_DIM + s * 16 + 8 * lhi);
                }
                #pragma unroll
                for (int i = 0; i < 2; i++)
                    #pragma unroll
                    for (int j = 0; j < 2; j++)
                        acc[i][j] = __builtin_amdgcn_mfma_f32_32x32x16_bf16(a[i], b[j], acc[i][j], 0, 0, 0);
            }

            #pragma unroll
            for (int i = 0; i < 2; i++)
                #pragma unroll
                for (int j = 0; j < 2; j++)
                    #pragma unroll
                    for (int r = 0; r < 16; r++) {
                        int m   = (r & 3) + 8 * (r >> 2) + 4 * lhi;
                        int row = R + i * 32 + m;
                        int col = C + j * 32 + l31;
                        __builtin_nontemporal_store(acc[i][j][r],
                                                    &recon[(size_t)row * N_NODES + col]);
                    }
        }
    }
}

// ================================================================ FALLBACK
// Verified R3 5-kernel path, used if cooperative launch is unavailable.
#define PREP_SPLITX_BLOCKS 4096
#define PREP_W1T_BLOCKS    512
#define PREP_ROWPTR_BLOCKS 33
__global__ __launch_bounds__(256) void prep(const float* __restrict__ x,
                                            short* __restrict__ xhi,
                                            short* __restrict__ xlo,
                                            const float* __restrict__ w1,
                                            short* __restrict__ w1t_hi,
                                            short* __restrict__ w1t_lo,
                                            const int* __restrict__ edge_row,
                                            int* __restrict__ row_ptr) {
    int b = blockIdx.x;
    if (b < PREP_SPLITX_BLOCKS) {
        size_t gid = (size_t)b * 256 + threadIdx.x;
        f32x4 v = *(const f32x4*)(x + gid * 4);
        s16x4 h, l;
        #pragma unroll
        for (int j = 0; j < 4; j++) {
            short hb = bf16_bits(v[j]);
            h[j] = hb;
            l[j] = bf16_bits(v[j] - bits_to_f32(hb));
        }
        *(s16x4*)(xhi + gid * 4) = h;
        *(s16x4*)(xlo + gid * 4) = l;
    } else if (b < PREP_SPLITX_BLOCKS + PREP_W1T_BLOCKS) {
        int id = (b - PREP_SPLITX_BLOCKS) * 256 + threadIdx.x;
        int k = id / HID_DIM, n = id % HID_DIM;
        float v = w1[id];
        short hb = bf16_bits(v);
        w1t_hi[(size_t)n * IN_DIM + k] = hb;
        w1t_lo[(size_t)n * IN_DIM + k] = bf16_bits(v - bits_to_f32(hb));
    } else {
        int i = (b - PREP_SPLITX_BLOCKS - PREP_W1T_BLOCKS) * 256 + threadIdx.x;
        if (i > N_NODES) return;
        int lo = 0, hi = E_EDGES;
        while (lo < hi) {
            int mid = (lo + hi) >> 1;
            if (edge_row[mid] < i) lo = mid + 1; else hi = mid;
        }
        row_ptr[i] = lo;
    }
}

__global__ __launch_bounds__(512) void gemm1_mfma(const short* __restrict__ xhi,
                                                  const short* __restrict__ xlo,
                                                  const short* __restrict__ bhi,
                                                  const short* __restrict__ blo,
                                                  float* __restrict__ support) {
    __shared__ __align__(16) short ldsA[2][128 * 64];
    __shared__ __align__(16) short ldsB[2][64 * 64];
    const int tid  = threadIdx.x;
    const int wave = tid >> 6, lane = tid & 63;
    const int wr = wave >> 1, wc = wave & 1;
    const int R0 = blockIdx.y * 128;
    const int C0 = blockIdx.x * 64;
    const int l31 = lane & 31, lhi = lane >> 5;

    const int rowA = 32 * wr + l31;
    const int rowB = 32 * wc + l31;
    const int baseA = (rowA * 128 + 16 * lhi);
    const int baseB = (rowB * 128 + 16 * lhi);
    const int swzA = (rowA & 7) << 4;
    const int swzB = (rowB & 7) << 4;

    f32x16 acc = 0.f;

    for (int k0 = 0; k0 < IN_DIM; k0 += 64) {
        #pragma unroll
        for (int j = 0; j < 2; j++) {
            int ch = tid + 512 * j;
            int r  = ch >> 3;
            int sc = (ch & 7) ^ (r & 7);
            size_t goff = (size_t)(R0 + r) * IN_DIM + k0 + sc * 8;
            gload_lds16(xhi + goff, &ldsA[0][ch * 8]);
            gload_lds16(xlo + goff, &ldsA[1][ch * 8]);
        }
        {
            int ch = tid;
            int r  = ch >> 3;
            int sc = (ch & 7) ^ (r & 7);
            size_t goff = (size_t)(C0 + r) * IN_DIM + k0 + sc * 8;
            gload_lds16(bhi + goff, &ldsB[0][ch * 8]);
            gload_lds16(blo + goff, &ldsB[1][ch * 8]);
        }
        __syncthreads();

        #pragma unroll
        for (int kk = 0; kk < 4; kk++) {
            int boffA = (baseA + kk * 32) ^ swzA;
            int boffB = (baseB + kk * 32) ^ swzB;
            s16x8 ah = *(const s16x8*)((const char*)&ldsA[0][0] + boffA);
            s16x8 al = *(const s16x8*)((const char*)&ldsA[1][0] + boffA);
            s16x8 bh = *(const s16x8*)((const char*)&ldsB[0][0] + boffB);
            s16x8 bl = *(const s16x8*)((const char*)&ldsB[1][0] + boffB);
            acc = __builtin_amdgcn_mfma_f32_32x32x16_bf16(ah, bh, acc, 0, 0, 0);
            acc = __builtin_amdgcn_mfma_f32_32x32x16_bf16(al, bh, acc, 0, 0, 0);
            acc = __builtin_amdgcn_mfma_f32_32x32x16_bf16(ah, bl, acc, 0, 0, 0);
        }
        __syncthreads();
    }

    const int R = R0 + wr * 32, C = C0 + wc * 32;
    #pragma unroll
    for (int r = 0; r < 16; r++) {
        int m = (r & 3) + 8 * (r >> 2) + 4 * lhi;
        support[(size_t)(R + m) * HID_DIM + C + l31] = acc[r];
    }
}

__global__ __launch_bounds__(256) void spmm1_gemm2(const float* __restrict__ support,
                                                   const int* __restrict__ row_ptr,
                                                   const int* __restrict__ edge_col,
                                                   const float* __restrict__ edge_weight,
                                                   const float* __restrict__ w2,
                                                   float* __restrict__ zpre) {
    __shared__ __align__(16) f32x4 hrow[4][64];
    const int wave = threadIdx.x >> 6, lane = threadIdx.x & 63;
    const int row = blockIdx.x * 4 + wave;
    const int s = row_ptr[row], e = row_ptr[row + 1];
    const int d = lane * 4;
    f32x4 acc = 0.f;
    int i = s;
    for (; i + 4 <= e; i += 4) {
        int   c0 = edge_col[i],     c1 = edge_col[i + 1];
        int   c2 = edge_col[i + 2], c3 = edge_col[i + 3];
        float w0 = edge_weight[i],     w1 = edge_weight[i + 1];
        float w2v = edge_weight[i + 2], w3 = edge_weight[i + 3];
        f32x4 v0 = *(const f32x4*)(support + (size_t)c0 * HID_DIM + d);
        f32x4 v1 = *(const f32x4*)(support + (size_t)c1 * HID_DIM + d);
        f32x4 v2 = *(const f32x4*)(support + (size_t)c2 * HID_DIM + d);
        f32x4 v3 = *(const f32x4*)(support + (size_t)c3 * HID_DIM + d);
        #pragma unroll
        for (int j = 0; j < 4; j++)
            acc[j] = fmaf(w0, v0[j], fmaf(w1, v1[j], fmaf(w2v, v2[j], fmaf(w3, v3[j], acc[j]))));
    }
    for (; i < e; i++) {
        int   c = edge_col[i];
        float w = edge_weight[i];
        f32x4 v = *(const f32x4*)(support + (size_t)c * HID_DIM + d);
        #pragma unroll
        for (int j = 0; j < 4; j++) acc[j] = fmaf(w, v[j], acc[j]);
    }
    f32x4 r;
    #pragma unroll
    for (int j = 0; j < 4; j++) r[j] = fmaxf(acc[j], 0.f);
    hrow[wave][lane] = r;
    __syncthreads();

    float z = 0.f;
    #pragma unroll 8
    for (int k4 = 0; k4 < HID_DIM / 4; k4++) {
        f32x4 h4 = hrow[wave][k4];
        #pragma unroll
        for (int t = 0; t < 4; t++)
            z = fmaf(h4[t], w2[(size_t)(k4 * 4 + t) * Z_DIM + lane], z);
    }
    zpre[(size_t)row * Z_DIM + lane] = z;
}

__global__ __launch_bounds__(256) void spmm2(const float* __restrict__ zpre,
                                             const int* __restrict__ row_ptr,
                                             const int* __restrict__ edge_col,
                                             const float* __restrict__ edge_weight,
                                             float* __restrict__ z_out,
                                             __hip_bfloat16* __restrict__ zb) {
    const int wave = threadIdx.x >> 6, lane = threadIdx.x & 63;
    const int row = blockIdx.x * 4 + wave;
    const int s = row_ptr[row], e = row_ptr[row + 1];
    float acc = 0.f;
    int i = s;
    for (; i + 4 <= e; i += 4) {
        int   c0 = edge_col[i],     c1 = edge_col[i + 1];
        int   c2 = edge_col[i + 2], c3 = edge_col[i + 3];
        float w0 = edge_weight[i],     w1 = edge_weight[i + 1];
        float w2 = edge_weight[i + 2], w3 = edge_weight[i + 3];
        float v0 = zpre[(size_t)c0 * Z_DIM + lane];
        float v1 = zpre[(size_t)c1 * Z_DIM + lane];
        float v2 = zpre[(size_t)c2 * Z_DIM + lane];
        float v3 = zpre[(size_t)c3 * Z_DIM + lane];
        acc = fmaf(w0, v0, fmaf(w1, v1, fmaf(w2, v2, fmaf(w3, v3, acc))));
    }
    for (; i < e; i++)
        acc = fmaf(edge_weight[i], zpre[(size_t)edge_col[i] * Z_DIM + lane], acc);
    z_out[(size_t)row * Z_DIM + lane] = acc;
    zb[(size_t)row * Z_DIM + lane]    = __float2bfloat16(acc);
}

__global__ __launch_bounds__(256) void recon_mfma(const __hip_bfloat16* __restrict__ zb,
                                                  float* __restrict__ recon) {
    const int wave = threadIdx.x >> 6;
    const int lane = threadIdx.x & 63;
    const int wr = wave >> 1, wc = wave & 1;
    const int R = blockIdx.y * 128 + wr * 64;
    const int C = blockIdx.x * 128 + wc * 64;
    const int l31 = lane & 31;
    const int lhi = lane >> 5;
    const short* zs = (const short*)zb;

    f32x16 acc[2][2];
    #pragma unroll
    for (int i = 0; i < 2; i++)
        #pragma unroll
        for (int j = 0; j < 2; j++) acc[i][j] = 0.f;

    #pragma unroll
    for (int s = 0; s < 4; s++) {
        s16x8 a[2], b[2];
        #pragma unroll
        for (int i = 0; i < 2; i++) {
            a[i] = *(const s16x8*)(zs + (size_t)(R + i * 32 + l31) * Z_DIM + s * 16 + 8 * lhi);
            b[i] = *(const s16x8*)(zs + (size_t)(C + i * 32 + l31) * Z_DIM + s * 16 + 8 * lhi);
        }
        #pragma unroll
        for (int i = 0; i < 2; i++)
            #pragma unroll
            for (int j = 0; j < 2; j++)
                acc[i][j] = __builtin_amdgcn_mfma_f32_32x32x16_bf16(a[i], b[j], acc[i][j], 0, 0, 0);
    }

    #pragma unroll
    for (int i = 0; i < 2; i++)
        #pragma unroll
        for (int j = 0; j < 2; j++)
            #pragma unroll
            for (int r = 0; r < 16; r++) {
                int m   = (r & 3) + 8 * (r >> 2) + 4 * lhi;
                int row = R + i * 32 + m;
                int col = C + j * 32 + l31;
                __builtin_nontemporal_store(acc[i][j][r], &recon[(size_t)row * N_NODES + col]);
            }
}

// ---------------------------------------------------------------- launch
extern "C" void kernel_launch(void* const* d_in, const int* in_sizes, int n_in,
                              void* d_out, int out_size, void* d_ws, size_t ws_size,
                              hipStream_t stream) {
    const float* x           = (const float*)d_in[0];
    const float* w1          = (const float*)d_in[1];
    const float* w2          = (const float*)d_in[2];
    const int*   edge_row    = (const int*)d_in[3];
    const int*   edge_col    = (const int*)d_in[4];
    const float* edge_weight = (const float*)d_in[5];

    float* recon = (float*)d_out;                                   // [N, N]
    float* z_out = recon + (size_t)N_NODES * N_NODES;               // [N, Z_DIM]

    // workspace layout
    char* ws = (char*)d_ws;
    short* xhi    = (short*)ws;                          ws += (size_t)N_NODES * IN_DIM * 2;   // 8 MB
    short* xlo    = (short*)ws;                          ws += (size_t)N_NODES * IN_DIM * 2;   // 8 MB
    short* w1t_hi = (short*)ws;                          ws += (size_t)HID_DIM * IN_DIM * 2;   // 256 KB
    short* w1t_lo = (short*)ws;                          ws += (size_t)HID_DIM * IN_DIM * 2;   // 256 KB
    float* support = (float*)ws;                         ws += (size_t)N_NODES * HID_DIM * 4;  // 8 MB
    float* zpre    = (float*)ws;                         ws += (size_t)N_NODES * Z_DIM * 4;    // 2 MB
    __hip_bfloat16* zb = (__hip_bfloat16*)ws;            ws += (size_t)N_NODES * Z_DIM * 2;    // 1 MB
    int* row_ptr   = (int*)ws;

    void* args[] = { (void*)&x, (void*)&w1, (void*)&w2,
                     (void*)&edge_row, (void*)&edge_col, (void*)&edge_weight,
                     (void*)&xhi, (void*)&xlo, (void*)&w1t_hi, (void*)&w1t_lo,
                     (void*)&support, (void*)&zpre, (void*)&zb, (void*)&row_ptr,
                     (void*)&z_out, (void*)&recon };
    hipError_t err = hipLaunchCooperativeKernel((const void*)gcn_mega,
                                                dim3(256), dim3(512), args, 0, stream);
    if (err != hipSuccess) {
        // fallback: verified 5-kernel path
        prep<<<PREP_SPLITX_BLOCKS + PREP_W1T_BLOCKS + PREP_ROWPTR_BLOCKS, 256, 0, stream>>>(
            x, xhi, xlo, w1, w1t_hi, w1t_lo, edge_row, row_ptr);
        gemm1_mfma<<<dim3(HID_DIM / 64, N_NODES / 128), 512, 0, stream>>>(
            xhi, xlo, w1t_hi, w1t_lo, support);
        spmm1_gemm2<<<N_NODES / 4, 256, 0, stream>>>(support, row_ptr, edge_col, edge_weight,
                                                     w2, zpre);
        spmm2<<<N_NODES / 4, 256, 0, stream>>>(zpre, row_ptr, edge_col, edge_weight, z_out, zb);
        recon_mfma<<<dim3(N_NODES / 128, N_NODES / 128), 256, 0, stream>>>(zb, recon);
    }
}

// Round 6
// 357.796 us; speedup vs baseline: 1.5647x; 1.5647x over previous
//
#include <hip/hip_runtime.h>
#include <hip/hip_bf16.h>

#define N_NODES 8192
#define E_EDGES 262144
#define IN_DIM  512
#define HID_DIM 256
#define Z_DIM   64

typedef float f32x4  __attribute__((ext_vector_type(4)));
typedef float f32x16 __attribute__((ext_vector_type(16)));
typedef short s16x4  __attribute__((ext_vector_type(4)));
typedef short s16x8  __attribute__((ext_vector_type(8)));

static __device__ __forceinline__ short bf16_bits(float f) {
    __hip_bfloat16 b = __float2bfloat16(f);
    return *reinterpret_cast<short*>(&b);
}
static __device__ __forceinline__ float bits_to_f32(short s) {
    __hip_bfloat16 b = *reinterpret_cast<__hip_bfloat16*>(&s);
    return __bfloat162float(b);
}

static __device__ __forceinline__ void gload_lds16(const void* g, void* l) {
    __builtin_amdgcn_global_load_lds((const __attribute__((address_space(1))) void*)g,
                                     (__attribute__((address_space(3))) void*)l, 16, 0, 0);
}

// ---------------------------------------------------------------- fused prep
// blocks [0,4096): split_x ; [4096,4608): split_w1t ; [4608,4641): build_rowptr
#define PREP_SPLITX_BLOCKS 4096
#define PREP_W1T_BLOCKS    512
#define PREP_ROWPTR_BLOCKS 33
__global__ __launch_bounds__(256) void prep(const float* __restrict__ x,
                                            short* __restrict__ xhi,
                                            short* __restrict__ xlo,
                                            const float* __restrict__ w1,
                                            short* __restrict__ w1t_hi,
                                            short* __restrict__ w1t_lo,
                                            const int* __restrict__ edge_row,
                                            int* __restrict__ row_ptr) {
    int b = blockIdx.x;
    if (b < PREP_SPLITX_BLOCKS) {
        // x[8192][512] f32 -> xhi, xlo bf16 (Ozaki split)
        size_t gid = (size_t)b * 256 + threadIdx.x;
        f32x4 v = *(const f32x4*)(x + gid * 4);
        s16x4 h, l;
        #pragma unroll
        for (int j = 0; j < 4; j++) {
            short hb = bf16_bits(v[j]);
            h[j] = hb;
            l[j] = bf16_bits(v[j] - bits_to_f32(hb));
        }
        *(s16x4*)(xhi + gid * 4) = h;
        *(s16x4*)(xlo + gid * 4) = l;
    } else if (b < PREP_SPLITX_BLOCKS + PREP_W1T_BLOCKS) {
        // w1[512][256] -> w1t_hi/lo[256][512] bf16
        int id = (b - PREP_SPLITX_BLOCKS) * 256 + threadIdx.x;
        int k = id / HID_DIM, n = id % HID_DIM;
        float v = w1[id];
        short hb = bf16_bits(v);
        w1t_hi[(size_t)n * IN_DIM + k] = hb;
        w1t_lo[(size_t)n * IN_DIM + k] = bf16_bits(v - bits_to_f32(hb));
    } else {
        int i = (b - PREP_SPLITX_BLOCKS - PREP_W1T_BLOCKS) * 256 + threadIdx.x;
        if (i > N_NODES) return;
        int lo = 0, hi = E_EDGES;
        while (lo < hi) {
            int mid = (lo + hi) >> 1;
            if (edge_row[mid] < i) lo = mid + 1; else hi = mid;
        }
        row_ptr[i] = lo;
    }
}

// ---------------------------------------------------------------- gemm1: support = x @ w1
// LDS-tiled split-bf16 MFMA 32x32x16, 3 products (Ah*Bh + Al*Bh + Ah*Bl), fp32 accum.
// Block tile 128(M)x64(N), BK=64; 8 waves (4x2), each wave one 32x32 output tile.
// Grid (4,64)=256 blocks = 1/CU, 8 waves/CU. Staging: global_load_lds width 16 with
// T2 XOR-swizzle (linear LDS dest, inverse-swizzled global SOURCE, swizzled ds_read).
// K-order identical to previous version (bitwise-same accumulation).
__global__ __launch_bounds__(512) void gemm1_mfma(const short* __restrict__ xhi,
                                                  const short* __restrict__ xlo,
                                                  const short* __restrict__ bhi,
                                                  const short* __restrict__ blo,
                                                  float* __restrict__ support) {
    __shared__ __align__(16) short ldsA[2][128 * 64];   // Ah, Al (16 KB each)
    __shared__ __align__(16) short ldsB[2][64 * 64];    // Bh, Bl (8 KB each)
    const int tid  = threadIdx.x;
    const int wave = tid >> 6, lane = tid & 63;
    const int wr = wave >> 1, wc = wave & 1;            // 4 x 2 waves
    const int R0 = blockIdx.y * 128;
    const int C0 = blockIdx.x * 64;
    const int l31 = lane & 31, lhi = lane >> 5;

    // ds_read byte offsets (swizzled), invariant over k-tiles
    const int rowA = 32 * wr + l31;                     // 0..127
    const int rowB = 32 * wc + l31;                     // 0..63
    const int baseA = (rowA * 128 + 16 * lhi);
    const int baseB = (rowB * 128 + 16 * lhi);
    const int swzA = (rowA & 7) << 4;
    const int swzB = (rowB & 7) << 4;

    f32x16 acc = 0.f;

    for (int k0 = 0; k0 < IN_DIM; k0 += 64) {
        // ---- stage A (128x64, 1024 chunks of 16B, 2/thread) and B (64x64, 512 chunks, 1/thread)
        #pragma unroll
        for (int j = 0; j < 2; j++) {
            int ch = tid + 512 * j;
            int r  = ch >> 3;                  // tile row (8 chunks per 128B row)
            int sc = (ch & 7) ^ (r & 7);       // inverse-swizzled source column-chunk
            size_t goff = (size_t)(R0 + r) * IN_DIM + k0 + sc * 8;
            gload_lds16(xhi + goff, &ldsA[0][ch * 8]);
            gload_lds16(xlo + goff, &ldsA[1][ch * 8]);
        }
        {
            int ch = tid;
            int r  = ch >> 3;
            int sc = (ch & 7) ^ (r & 7);
            size_t goff = (size_t)(C0 + r) * IN_DIM + k0 + sc * 8;
            gload_lds16(bhi + goff, &ldsB[0][ch * 8]);
            gload_lds16(blo + goff, &ldsB[1][ch * 8]);
        }
        __syncthreads();

        #pragma unroll
        for (int kk = 0; kk < 4; kk++) {
            int boffA = (baseA + kk * 32) ^ swzA;
            int boffB = (baseB + kk * 32) ^ swzB;
            s16x8 ah = *(const s16x8*)((const char*)&ldsA[0][0] + boffA);
            s16x8 al = *(const s16x8*)((const char*)&ldsA[1][0] + boffA);
            s16x8 bh = *(const s16x8*)((const char*)&ldsB[0][0] + boffB);
            s16x8 bl = *(const s16x8*)((const char*)&ldsB[1][0] + boffB);
            acc = __builtin_amdgcn_mfma_f32_32x32x16_bf16(ah, bh, acc, 0, 0, 0);
            acc = __builtin_amdgcn_mfma_f32_32x32x16_bf16(al, bh, acc, 0, 0, 0);
            acc = __builtin_amdgcn_mfma_f32_32x32x16_bf16(ah, bl, acc, 0, 0, 0);
        }
        __syncthreads();
    }

    const int R = R0 + wr * 32, C = C0 + wc * 32;
    #pragma unroll
    for (int r = 0; r < 16; r++) {
        int m = (r & 3) + 8 * (r >> 2) + 4 * lhi;
        support[(size_t)(R + m) * HID_DIM + C + l31] = acc[r];
    }
}

// ---------------------------------------------------------------- SPMM1 + relu + (h @ W2) fused
// One wave per row; lane covers dims 4*lane..4*lane+3 (f32x4 gather = full 1KB row/instr).
// Edge loop 8-deep (two nested 4-chains == sequential 4-deep iterations, bit-identical;
// empirically confirmed by R5 mega absmax). 8 gathers in flight per wave for latency hiding.
// After relu, h-row bounces through LDS; each lane computes zpre[row][lane] with the
// same ascending-k fmaf chain as the original gemm_f32 (bit-identical z).
__global__ __launch_bounds__(256) void spmm1_gemm2(const float* __restrict__ support,
                                                   const int* __restrict__ row_ptr,
                                                   const int* __restrict__ edge_col,
                                                   const float* __restrict__ edge_weight,
                                                   const float* __restrict__ w2,
                                                   float* __restrict__ zpre) {
    __shared__ __align__(16) f32x4 hrow[4][64];
    const int wave = threadIdx.x >> 6, lane = threadIdx.x & 63;
    const int row = blockIdx.x * 4 + wave;
    const int s = row_ptr[row], e = row_ptr[row + 1];
    const int d = lane * 4;
    f32x4 acc = 0.f;
    int i = s;
    for (; i + 8 <= e; i += 8) {
        int   c0 = edge_col[i],     c1 = edge_col[i + 1];
        int   c2 = edge_col[i + 2], c3 = edge_col[i + 3];
        int   c4 = edge_col[i + 4], c5 = edge_col[i + 5];
        int   c6 = edge_col[i + 6], c7 = edge_col[i + 7];
        float w0 = edge_weight[i],     w1v = edge_weight[i + 1];
        float w2v = edge_weight[i + 2], w3 = edge_weight[i + 3];
        float w4 = edge_weight[i + 4], w5 = edge_weight[i + 5];
        float w6 = edge_weight[i + 6], w7 = edge_weight[i + 7];
        f32x4 v0 = *(const f32x4*)(support + (size_t)c0 * HID_DIM + d);
        f32x4 v1 = *(const f32x4*)(support + (size_t)c1 * HID_DIM + d);
        f32x4 v2 = *(const f32x4*)(support + (size_t)c2 * HID_DIM + d);
        f32x4 v3 = *(const f32x4*)(support + (size_t)c3 * HID_DIM + d);
        f32x4 v4 = *(const f32x4*)(support + (size_t)c4 * HID_DIM + d);
        f32x4 v5 = *(const f32x4*)(support + (size_t)c5 * HID_DIM + d);
        f32x4 v6 = *(const f32x4*)(support + (size_t)c6 * HID_DIM + d);
        f32x4 v7 = *(const f32x4*)(support + (size_t)c7 * HID_DIM + d);
        #pragma unroll
        for (int j = 0; j < 4; j++) {
            float t = fmaf(w0, v0[j], fmaf(w1v, v1[j], fmaf(w2v, v2[j], fmaf(w3, v3[j], acc[j]))));
            acc[j]  = fmaf(w4, v4[j], fmaf(w5,  v5[j], fmaf(w6,  v6[j], fmaf(w7, v7[j], t))));
        }
    }
    for (; i + 4 <= e; i += 4) {
        int   c0 = edge_col[i],     c1 = edge_col[i + 1];
        int   c2 = edge_col[i + 2], c3 = edge_col[i + 3];
        float w0 = edge_weight[i],     w1v = edge_weight[i + 1];
        float w2v = edge_weight[i + 2], w3 = edge_weight[i + 3];
        f32x4 v0 = *(const f32x4*)(support + (size_t)c0 * HID_DIM + d);
        f32x4 v1 = *(const f32x4*)(support + (size_t)c1 * HID_DIM + d);
        f32x4 v2 = *(const f32x4*)(support + (size_t)c2 * HID_DIM + d);
        f32x4 v3 = *(const f32x4*)(support + (size_t)c3 * HID_DIM + d);
        #pragma unroll
        for (int j = 0; j < 4; j++)
            acc[j] = fmaf(w0, v0[j], fmaf(w1v, v1[j], fmaf(w2v, v2[j], fmaf(w3, v3[j], acc[j]))));
    }
    for (; i < e; i++) {
        int   c = edge_col[i];
        float w = edge_weight[i];
        f32x4 v = *(const f32x4*)(support + (size_t)c * HID_DIM + d);
        #pragma unroll
        for (int j = 0; j < 4; j++) acc[j] = fmaf(w, v[j], acc[j]);
    }
    f32x4 r;
    #pragma unroll
    for (int j = 0; j < 4; j++) r[j] = fmaxf(acc[j], 0.f);
    hrow[wave][lane] = r;
    __syncthreads();

    // z = h @ W2, ascending-k scalar fmaf chain (matches original gemm_f32 order)
    float z = 0.f;
    #pragma unroll 8
    for (int k4 = 0; k4 < HID_DIM / 4; k4++) {
        f32x4 h4 = hrow[wave][k4];          // LDS broadcast (all lanes same addr)
        #pragma unroll
        for (int t = 0; t < 4; t++)
            z = fmaf(h4[t], w2[(size_t)(k4 * 4 + t) * Z_DIM + lane], z);
    }
    zpre[(size_t)row * Z_DIM + lane] = z;
}

// ---------------------------------------------------------------- SPMM2 (8-deep unroll)
__global__ __launch_bounds__(256) void spmm2(const float* __restrict__ zpre,
                                             const int* __restrict__ row_ptr,
                                             const int* __restrict__ edge_col,
                                             const float* __restrict__ edge_weight,
                                             float* __restrict__ z_out,
                                             __hip_bfloat16* __restrict__ zb) {
    const int wave = threadIdx.x >> 6, lane = threadIdx.x & 63;
    const int row = blockIdx.x * 4 + wave;
    const int s = row_ptr[row], e = row_ptr[row + 1];
    float acc = 0.f;
    int i = s;
    for (; i + 8 <= e; i += 8) {
        int   c0 = edge_col[i],     c1 = edge_col[i + 1];
        int   c2 = edge_col[i + 2], c3 = edge_col[i + 3];
        int   c4 = edge_col[i + 4], c5 = edge_col[i + 5];
        int   c6 = edge_col[i + 6], c7 = edge_col[i + 7];
        float w0 = edge_weight[i],     w1v = edge_weight[i + 1];
        float w2v = edge_weight[i + 2], w3 = edge_weight[i + 3];
        float w4 = edge_weight[i + 4], w5 = edge_weight[i + 5];
        float w6 = edge_weight[i + 6], w7 = edge_weight[i + 7];
        float v0 = zpre[(size_t)c0 * Z_DIM + lane];
        float v1 = zpre[(size_t)c1 * Z_DIM + lane];
        float v2 = zpre[(size_t)c2 * Z_DIM + lane];
        float v3 = zpre[(size_t)c3 * Z_DIM + lane];
        float v4 = zpre[(size_t)c4 * Z_DIM + lane];
        float v5 = zpre[(size_t)c5 * Z_DIM + lane];
        float v6 = zpre[(size_t)c6 * Z_DIM + lane];
        float v7 = zpre[(size_t)c7 * Z_DIM + lane];
        float t = fmaf(w0, v0, fmaf(w1v, v1, fmaf(w2v, v2, fmaf(w3, v3, acc))));
        acc     = fmaf(w4, v4, fmaf(w5,  v5, fmaf(w6,  v6, fmaf(w7, v7, t))));
    }
    for (; i + 4 <= e; i += 4) {
        int   c0 = edge_col[i],     c1 = edge_col[i + 1];
        int   c2 = edge_col[i + 2], c3 = edge_col[i + 3];
        float w0 = edge_weight[i],     w1v = edge_weight[i + 1];
        float w2v = edge_weight[i + 2], w3 = edge_weight[i + 3];
        float v0 = zpre[(size_t)c0 * Z_DIM + lane];
        float v1 = zpre[(size_t)c1 * Z_DIM + lane];
        float v2 = zpre[(size_t)c2 * Z_DIM + lane];
        float v3 = zpre[(size_t)c3 * Z_DIM + lane];
        acc = fmaf(w0, v0, fmaf(w1v, v1, fmaf(w2v, v2, fmaf(w3, v3, acc))));
    }
    for (; i < e; i++)
        acc = fmaf(edge_weight[i], zpre[(size_t)edge_col[i] * Z_DIM + lane], acc);
    z_out[(size_t)row * Z_DIM + lane] = acc;
    zb[(size_t)row * Z_DIM + lane]    = __float2bfloat16(acc);
}

// ---------------------------------------------------------------- recon = z @ z^T
// Output is write-once / never re-read: nontemporal stores keep 268 MB out of L2.
// Write-BW-bound (~42 us floor at the measured ~6.5 TB/s fill write BW).
__global__ __launch_bounds__(256) void recon_mfma(const __hip_bfloat16* __restrict__ zb,
                                                  float* __restrict__ recon) {
    const int wave = threadIdx.x >> 6;
    const int lane = threadIdx.x & 63;
    const int wr = wave >> 1, wc = wave & 1;
    const int R = blockIdx.y * 128 + wr * 64;
    const int C = blockIdx.x * 128 + wc * 64;
    const int l31 = lane & 31;
    const int lhi = lane >> 5;
    const short* zs = (const short*)zb;

    f32x16 acc[2][2];
    #pragma unroll
    for (int i = 0; i < 2; i++)
        #pragma unroll
        for (int j = 0; j < 2; j++) acc[i][j] = 0.f;

    #pragma unroll
    for (int s = 0; s < 4; s++) {
        s16x8 a[2], b[2];
        #pragma unroll
        for (int i = 0; i < 2; i++) {
            a[i] = *(const s16x8*)(zs + (size_t)(R + i * 32 + l31) * Z_DIM + s * 16 + 8 * lhi);
            b[i] = *(const s16x8*)(zs + (size_t)(C + i * 32 + l31) * Z_DIM + s * 16 + 8 * lhi);
        }
        #pragma unroll
        for (int i = 0; i < 2; i++)
            #pragma unroll
            for (int j = 0; j < 2; j++)
                acc[i][j] = __builtin_amdgcn_mfma_f32_32x32x16_bf16(a[i], b[j], acc[i][j], 0, 0, 0);
    }

    #pragma unroll
    for (int i = 0; i < 2; i++)
        #pragma unroll
        for (int j = 0; j < 2; j++)
            #pragma unroll
            for (int r = 0; r < 16; r++) {
                int m   = (r & 3) + 8 * (r >> 2) + 4 * lhi;
                int row = R + i * 32 + m;
                int col = C + j * 32 + l31;
                __builtin_nontemporal_store(acc[i][j][r], &recon[(size_t)row * N_NODES + col]);
            }
}

// ---------------------------------------------------------------- launch
extern "C" void kernel_launch(void* const* d_in, const int* in_sizes, int n_in,
                              void* d_out, int out_size, void* d_ws, size_t ws_size,
                              hipStream_t stream) {
    const float* x           = (const float*)d_in[0];
    const float* w1          = (const float*)d_in[1];
    const float* w2          = (const float*)d_in[2];
    const int*   edge_row    = (const int*)d_in[3];
    const int*   edge_col    = (const int*)d_in[4];
    const float* edge_weight = (const float*)d_in[5];

    float* recon = (float*)d_out;                                   // [N, N]
    float* z_out = recon + (size_t)N_NODES * N_NODES;               // [N, Z_DIM]

    // workspace layout
    char* ws = (char*)d_ws;
    short* xhi    = (short*)ws;                          ws += (size_t)N_NODES * IN_DIM * 2;   // 8 MB
    short* xlo    = (short*)ws;                          ws += (size_t)N_NODES * IN_DIM * 2;   // 8 MB
    short* w1t_hi = (short*)ws;                          ws += (size_t)HID_DIM * IN_DIM * 2;   // 256 KB
    short* w1t_lo = (short*)ws;                          ws += (size_t)HID_DIM * IN_DIM * 2;   // 256 KB
    float* support = (float*)ws;                         ws += (size_t)N_NODES * HID_DIM * 4;  // 8 MB
    float* zpre    = (float*)ws;                         ws += (size_t)N_NODES * Z_DIM * 4;    // 2 MB
    __hip_bfloat16* zb = (__hip_bfloat16*)ws;            ws += (size_t)N_NODES * Z_DIM * 2;    // 1 MB
    int* row_ptr   = (int*)ws;

    prep<<<PREP_SPLITX_BLOCKS + PREP_W1T_BLOCKS + PREP_ROWPTR_BLOCKS, 256, 0, stream>>>(
        x, xhi, xlo, w1, w1t_hi, w1t_lo, edge_row, row_ptr);

    gemm1_mfma<<<dim3(HID_DIM / 64, N_NODES / 128), 512, 0, stream>>>(
        xhi, xlo, w1t_hi, w1t_lo, support);

    spmm1_gemm2<<<N_NODES / 4, 256, 0, stream>>>(support, row_ptr, edge_col, edge_weight,
                                                 w2, zpre);

    spmm2<<<N_NODES / 4, 256, 0, stream>>>(zpre, row_ptr, edge_col, edge_weight, z_out, zb);

    recon_mfma<<<dim3(N_NODES / 128, N_NODES / 128), 256, 0, stream>>>(zb, recon);
}

// Round 7
// 357.557 us; speedup vs baseline: 1.5658x; 1.0007x over previous
//
#include <hip/hip_runtime.h>
#include <hip/hip_bf16.h>

#define N_NODES 8192
#define E_EDGES 262144
#define IN_DIM  512
#define HID_DIM 256
#define Z_DIM   64

typedef float f32x4  __attribute__((ext_vector_type(4)));
typedef float f32x16 __attribute__((ext_vector_type(16)));
typedef short s16x4  __attribute__((ext_vector_type(4)));
typedef short s16x8  __attribute__((ext_vector_type(8)));

static __device__ __forceinline__ short bf16_bits(float f) {
    __hip_bfloat16 b = __float2bfloat16(f);
    return *reinterpret_cast<short*>(&b);
}
static __device__ __forceinline__ float bits_to_f32(short s) {
    __hip_bfloat16 b = *reinterpret_cast<__hip_bfloat16*>(&s);
    return __bfloat162float(b);
}

static __device__ __forceinline__ void gload_lds16(const void* g, void* l) {
    __builtin_amdgcn_global_load_lds((const __attribute__((address_space(1))) void*)g,
                                     (__attribute__((address_space(3))) void*)l, 16, 0, 0);
}

// ---------------------------------------------------------------- fused prep
// blocks [0,4096): split_x ; [4096,4608): split_w1t ; [4608,4641): build_rowptr
#define PREP_SPLITX_BLOCKS 4096
#define PREP_W1T_BLOCKS    512
#define PREP_ROWPTR_BLOCKS 33
__global__ __launch_bounds__(256) void prep(const float* __restrict__ x,
                                            short* __restrict__ xhi,
                                            short* __restrict__ xlo,
                                            const float* __restrict__ w1,
                                            short* __restrict__ w1t_hi,
                                            short* __restrict__ w1t_lo,
                                            const int* __restrict__ edge_row,
                                            int* __restrict__ row_ptr) {
    int b = blockIdx.x;
    if (b < PREP_SPLITX_BLOCKS) {
        // x[8192][512] f32 -> xhi, xlo bf16 (Ozaki split)
        size_t gid = (size_t)b * 256 + threadIdx.x;
        f32x4 v = *(const f32x4*)(x + gid * 4);
        s16x4 h, l;
        #pragma unroll
        for (int j = 0; j < 4; j++) {
            short hb = bf16_bits(v[j]);
            h[j] = hb;
            l[j] = bf16_bits(v[j] - bits_to_f32(hb));
        }
        *(s16x4*)(xhi + gid * 4) = h;
        *(s16x4*)(xlo + gid * 4) = l;
    } else if (b < PREP_SPLITX_BLOCKS + PREP_W1T_BLOCKS) {
        // w1[512][256] -> w1t_hi/lo[256][512] bf16
        int id = (b - PREP_SPLITX_BLOCKS) * 256 + threadIdx.x;
        int k = id / HID_DIM, n = id % HID_DIM;
        float v = w1[id];
        short hb = bf16_bits(v);
        w1t_hi[(size_t)n * IN_DIM + k] = hb;
        w1t_lo[(size_t)n * IN_DIM + k] = bf16_bits(v - bits_to_f32(hb));
    } else {
        int i = (b - PREP_SPLITX_BLOCKS - PREP_W1T_BLOCKS) * 256 + threadIdx.x;
        if (i > N_NODES) return;
        int lo = 0, hi = E_EDGES;
        while (lo < hi) {
            int mid = (lo + hi) >> 1;
            if (edge_row[mid] < i) lo = mid + 1; else hi = mid;
        }
        row_ptr[i] = lo;
    }
}

// ---------------------------------------------------------------- gemm1: support = x @ w1
// LDS-tiled split-bf16 MFMA 32x32x16, 3 products (Ah*Bh + Al*Bh + Ah*Bl), fp32 accum.
// Block tile 128(M)x64(N), BK=64; 8 waves (4x2), each wave one 32x32 output tile.
__global__ __launch_bounds__(512) void gemm1_mfma(const short* __restrict__ xhi,
                                                  const short* __restrict__ xlo,
                                                  const short* __restrict__ bhi,
                                                  const short* __restrict__ blo,
                                                  float* __restrict__ support) {
    __shared__ __align__(16) short ldsA[2][128 * 64];   // Ah, Al (16 KB each)
    __shared__ __align__(16) short ldsB[2][64 * 64];    // Bh, Bl (8 KB each)
    const int tid  = threadIdx.x;
    const int wave = tid >> 6, lane = tid & 63;
    const int wr = wave >> 1, wc = wave & 1;            // 4 x 2 waves
    const int R0 = blockIdx.y * 128;
    const int C0 = blockIdx.x * 64;
    const int l31 = lane & 31, lhi = lane >> 5;

    // ds_read byte offsets (swizzled), invariant over k-tiles
    const int rowA = 32 * wr + l31;                     // 0..127
    const int rowB = 32 * wc + l31;                     // 0..63
    const int baseA = (rowA * 128 + 16 * lhi);
    const int baseB = (rowB * 128 + 16 * lhi);
    const int swzA = (rowA & 7) << 4;
    const int swzB = (rowB & 7) << 4;

    f32x16 acc = 0.f;

    for (int k0 = 0; k0 < IN_DIM; k0 += 64) {
        // ---- stage A (128x64, 1024 chunks of 16B, 2/thread) and B (64x64, 512 chunks, 1/thread)
        #pragma unroll
        for (int j = 0; j < 2; j++) {
            int ch = tid + 512 * j;
            int r  = ch >> 3;                  // tile row (8 chunks per 128B row)
            int sc = (ch & 7) ^ (r & 7);       // inverse-swizzled source column-chunk
            size_t goff = (size_t)(R0 + r) * IN_DIM + k0 + sc * 8;
            gload_lds16(xhi + goff, &ldsA[0][ch * 8]);
            gload_lds16(xlo + goff, &ldsA[1][ch * 8]);
        }
        {
            int ch = tid;
            int r  = ch >> 3;
            int sc = (ch & 7) ^ (r & 7);
            size_t goff = (size_t)(C0 + r) * IN_DIM + k0 + sc * 8;
            gload_lds16(bhi + goff, &ldsB[0][ch * 8]);
            gload_lds16(blo + goff, &ldsB[1][ch * 8]);
        }
        __syncthreads();

        #pragma unroll
        for (int kk = 0; kk < 4; kk++) {
            int boffA = (baseA + kk * 32) ^ swzA;
            int boffB = (baseB + kk * 32) ^ swzB;
            s16x8 ah = *(const s16x8*)((const char*)&ldsA[0][0] + boffA);
            s16x8 al = *(const s16x8*)((const char*)&ldsA[1][0] + boffA);
            s16x8 bh = *(const s16x8*)((const char*)&ldsB[0][0] + boffB);
            s16x8 bl = *(const s16x8*)((const char*)&ldsB[1][0] + boffB);
            acc = __builtin_amdgcn_mfma_f32_32x32x16_bf16(ah, bh, acc, 0, 0, 0);
            acc = __builtin_amdgcn_mfma_f32_32x32x16_bf16(al, bh, acc, 0, 0, 0);
            acc = __builtin_amdgcn_mfma_f32_32x32x16_bf16(ah, bl, acc, 0, 0, 0);
        }
        __syncthreads();
    }

    const int R = R0 + wr * 32, C = C0 + wc * 32;
    #pragma unroll
    for (int r = 0; r < 16; r++) {
        int m = (r & 3) + 8 * (r >> 2) + 4 * lhi;
        support[(size_t)(R + m) * HID_DIM + C + l31] = acc[r];
    }
}

// ---------------------------------------------------------------- SPMM1 + relu + (h @ W2) fused
__global__ __launch_bounds__(256) void spmm1_gemm2(const float* __restrict__ support,
                                                   const int* __restrict__ row_ptr,
                                                   const int* __restrict__ edge_col,
                                                   const float* __restrict__ edge_weight,
                                                   const float* __restrict__ w2,
                                                   float* __restrict__ zpre) {
    __shared__ __align__(16) f32x4 hrow[4][64];
    const int wave = threadIdx.x >> 6, lane = threadIdx.x & 63;
    const int row = blockIdx.x * 4 + wave;
    const int s = row_ptr[row], e = row_ptr[row + 1];
    const int d = lane * 4;
    f32x4 acc = 0.f;
    int i = s;
    for (; i + 8 <= e; i += 8) {
        int   c0 = edge_col[i],     c1 = edge_col[i + 1];
        int   c2 = edge_col[i + 2], c3 = edge_col[i + 3];
        int   c4 = edge_col[i + 4], c5 = edge_col[i + 5];
        int   c6 = edge_col[i + 6], c7 = edge_col[i + 7];
        float w0 = edge_weight[i],     w1v = edge_weight[i + 1];
        float w2v = edge_weight[i + 2], w3 = edge_weight[i + 3];
        float w4 = edge_weight[i + 4], w5 = edge_weight[i + 5];
        float w6 = edge_weight[i + 6], w7 = edge_weight[i + 7];
        f32x4 v0 = *(const f32x4*)(support + (size_t)c0 * HID_DIM + d);
        f32x4 v1 = *(const f32x4*)(support + (size_t)c1 * HID_DIM + d);
        f32x4 v2 = *(const f32x4*)(support + (size_t)c2 * HID_DIM + d);
        f32x4 v3 = *(const f32x4*)(support + (size_t)c3 * HID_DIM + d);
        f32x4 v4 = *(const f32x4*)(support + (size_t)c4 * HID_DIM + d);
        f32x4 v5 = *(const f32x4*)(support + (size_t)c5 * HID_DIM + d);
        f32x4 v6 = *(const f32x4*)(support + (size_t)c6 * HID_DIM + d);
        f32x4 v7 = *(const f32x4*)(support + (size_t)c7 * HID_DIM + d);
        #pragma unroll
        for (int j = 0; j < 4; j++) {
            float t = fmaf(w0, v0[j], fmaf(w1v, v1[j], fmaf(w2v, v2[j], fmaf(w3, v3[j], acc[j]))));
            acc[j]  = fmaf(w4, v4[j], fmaf(w5,  v5[j], fmaf(w6,  v6[j], fmaf(w7, v7[j], t))));
        }
    }
    for (; i + 4 <= e; i += 4) {
        int   c0 = edge_col[i],     c1 = edge_col[i + 1];
        int   c2 = edge_col[i + 2], c3 = edge_col[i + 3];
        float w0 = edge_weight[i],     w1v = edge_weight[i + 1];
        float w2v = edge_weight[i + 2], w3 = edge_weight[i + 3];
        f32x4 v0 = *(const f32x4*)(support + (size_t)c0 * HID_DIM + d);
        f32x4 v1 = *(const f32x4*)(support + (size_t)c1 * HID_DIM + d);
        f32x4 v2 = *(const f32x4*)(support + (size_t)c2 * HID_DIM + d);
        f32x4 v3 = *(const f32x4*)(support + (size_t)c3 * HID_DIM + d);
        #pragma unroll
        for (int j = 0; j < 4; j++)
            acc[j] = fmaf(w0, v0[j], fmaf(w1v, v1[j], fmaf(w2v, v2[j], fmaf(w3, v3[j], acc[j]))));
    }
    for (; i < e; i++) {
        int   c = edge_col[i];
        float w = edge_weight[i];
        f32x4 v = *(const f32x4*)(support + (size_t)c * HID_DIM + d);
        #pragma unroll
        for (int j = 0; j < 4; j++) acc[j] = fmaf(w, v[j], acc[j]);
    }
    f32x4 r;
    #pragma unroll
    for (int j = 0; j < 4; j++) r[j] = fmaxf(acc[j], 0.f);
    hrow[wave][lane] = r;
    __syncthreads();

    // z = h @ W2, ascending-k scalar fmaf chain (matches original gemm_f32 order)
    float z = 0.f;
    #pragma unroll 8
    for (int k4 = 0; k4 < HID_DIM / 4; k4++) {
        f32x4 h4 = hrow[wave][k4];          // LDS broadcast (all lanes same addr)
        #pragma unroll
        for (int t = 0; t < 4; t++)
            z = fmaf(h4[t], w2[(size_t)(k4 * 4 + t) * Z_DIM + lane], z);
    }
    zpre[(size_t)row * Z_DIM + lane] = z;
}

// ---------------------------------------------------------------- SPMM2 (8-deep unroll)
__global__ __launch_bounds__(256) void spmm2(const float* __restrict__ zpre,
                                             const int* __restrict__ row_ptr,
                                             const int* __restrict__ edge_col,
                                             const float* __restrict__ edge_weight,
                                             float* __restrict__ z_out,
                                             __hip_bfloat16* __restrict__ zb) {
    const int wave = threadIdx.x >> 6, lane = threadIdx.x & 63;
    const int row = blockIdx.x * 4 + wave;
    const int s = row_ptr[row], e = row_ptr[row + 1];
    float acc = 0.f;
    int i = s;
    for (; i + 8 <= e; i += 8) {
        int   c0 = edge_col[i],     c1 = edge_col[i + 1];
        int   c2 = edge_col[i + 2], c3 = edge_col[i + 3];
        int   c4 = edge_col[i + 4], c5 = edge_col[i + 5];
        int   c6 = edge_col[i + 6], c7 = edge_col[i + 7];
        float w0 = edge_weight[i],     w1v = edge_weight[i + 1];
        float w2v = edge_weight[i + 2], w3 = edge_weight[i + 3];
        float w4 = edge_weight[i + 4], w5 = edge_weight[i + 5];
        float w6 = edge_weight[i + 6], w7 = edge_weight[i + 7];
        float v0 = zpre[(size_t)c0 * Z_DIM + lane];
        float v1 = zpre[(size_t)c1 * Z_DIM + lane];
        float v2 = zpre[(size_t)c2 * Z_DIM + lane];
        float v3 = zpre[(size_t)c3 * Z_DIM + lane];
        float v4 = zpre[(size_t)c4 * Z_DIM + lane];
        float v5 = zpre[(size_t)c5 * Z_DIM + lane];
        float v6 = zpre[(size_t)c6 * Z_DIM + lane];
        float v7 = zpre[(size_t)c7 * Z_DIM + lane];
        float t = fmaf(w0, v0, fmaf(w1v, v1, fmaf(w2v, v2, fmaf(w3, v3, acc))));
        acc     = fmaf(w4, v4, fmaf(w5,  v5, fmaf(w6,  v6, fmaf(w7, v7, t))));
    }
    for (; i + 4 <= e; i += 4) {
        int   c0 = edge_col[i],     c1 = edge_col[i + 1];
        int   c2 = edge_col[i + 2], c3 = edge_col[i + 3];
        float w0 = edge_weight[i],     w1v = edge_weight[i + 1];
        float w2v = edge_weight[i + 2], w3 = edge_weight[i + 3];
        float v0 = zpre[(size_t)c0 * Z_DIM + lane];
        float v1 = zpre[(size_t)c1 * Z_DIM + lane];
        float v2 = zpre[(size_t)c2 * Z_DIM + lane];
        float v3 = zpre[(size_t)c3 * Z_DIM + lane];
        acc = fmaf(w0, v0, fmaf(w1v, v1, fmaf(w2v, v2, fmaf(w3, v3, acc))));
    }
    for (; i < e; i++)
        acc = fmaf(edge_weight[i], zpre[(size_t)edge_col[i] * Z_DIM + lane], acc);
    z_out[(size_t)row * Z_DIM + lane] = acc;
    zb[(size_t)row * Z_DIM + lane]    = __float2bfloat16(acc);
}

// ---------------------------------------------------------------- recon = z @ z^T
// Epilogue v2: per-wave LDS transpose of each 32x32 accumulator quadrant into
// [32][36] (padded, conflict-free), then 4x fewer stores as f32x4 nontemporal
// (each instr covers 8x128B contiguous segments vs 2x128B scalar before).
// Values bit-identical (pure relocation); wave-local LDS so no barriers.
__global__ __launch_bounds__(256) void recon_mfma(const __hip_bfloat16* __restrict__ zb,
                                                  float* __restrict__ recon) {
    __shared__ __align__(16) float tb[4][32][36];       // 18.4 KB, one buf per wave
    const int wave = threadIdx.x >> 6;
    const int lane = threadIdx.x & 63;
    const int wr = wave >> 1, wc = wave & 1;
    const int R = blockIdx.y * 128 + wr * 64;
    const int C = blockIdx.x * 128 + wc * 64;
    const int l31 = lane & 31;
    const int lhi = lane >> 5;
    const short* zs = (const short*)zb;

    f32x16 acc[2][2];
    #pragma unroll
    for (int i = 0; i < 2; i++)
        #pragma unroll
        for (int j = 0; j < 2; j++) acc[i][j] = 0.f;

    #pragma unroll
    for (int s = 0; s < 4; s++) {
        s16x8 a[2], b[2];
        #pragma unroll
        for (int i = 0; i < 2; i++) {
            a[i] = *(const s16x8*)(zs + (size_t)(R + i * 32 + l31) * Z_DIM + s * 16 + 8 * lhi);
            b[i] = *(const s16x8*)(zs + (size_t)(C + i * 32 + l31) * Z_DIM + s * 16 + 8 * lhi);
        }
        #pragma unroll
        for (int i = 0; i < 2; i++)
            #pragma unroll
            for (int j = 0; j < 2; j++)
                acc[i][j] = __builtin_amdgcn_mfma_f32_32x32x16_bf16(a[i], b[j], acc[i][j], 0, 0, 0);
    }

    // transpose-and-store each 32x32 quadrant through wave-local LDS
    const int rrow = lane >> 3;          // 0..7 (8 rows per pass)
    const int rcol = (lane & 7) * 4;     // 0,4,...,28
    #pragma unroll
    for (int i = 0; i < 2; i++)
        #pragma unroll
        for (int j = 0; j < 2; j++) {
            #pragma unroll
            for (int r = 0; r < 16; r++) {
                int m = (r & 3) + 8 * (r >> 2) + 4 * lhi;      // row within quadrant
                tb[wave][m][l31] = acc[i][j][r];               // col = l31
            }
            // wave-local: compiler orders ds_write -> ds_read via lgkmcnt
            #pragma unroll
            for (int p = 0; p < 4; p++) {
                int row = p * 8 + rrow;
                f32x4 v = *(const f32x4*)&tb[wave][row][rcol];
                __builtin_nontemporal_store(
                    v, (f32x4*)&recon[(size_t)(R + i * 32 + row) * N_NODES + C + j * 32 + rcol]);
            }
        }
}

// ---------------------------------------------------------------- launch
extern "C" void kernel_launch(void* const* d_in, const int* in_sizes, int n_in,
                              void* d_out, int out_size, void* d_ws, size_t ws_size,
                              hipStream_t stream) {
    const float* x           = (const float*)d_in[0];
    const float* w1          = (const float*)d_in[1];
    const float* w2          = (const float*)d_in[2];
    const int*   edge_row    = (const int*)d_in[3];
    const int*   edge_col    = (const int*)d_in[4];
    const float* edge_weight = (const float*)d_in[5];

    float* recon = (float*)d_out;                                   // [N, N]
    float* z_out = recon + (size_t)N_NODES * N_NODES;               // [N, Z_DIM]

    // workspace layout
    char* ws = (char*)d_ws;
    short* xhi    = (short*)ws;                          ws += (size_t)N_NODES * IN_DIM * 2;   // 8 MB
    short* xlo    = (short*)ws;                          ws += (size_t)N_NODES * IN_DIM * 2;   // 8 MB
    short* w1t_hi = (short*)ws;                          ws += (size_t)HID_DIM * IN_DIM * 2;   // 256 KB
    short* w1t_lo = (short*)ws;                          ws += (size_t)HID_DIM * IN_DIM * 2;   // 256 KB
    float* support = (float*)ws;                         ws += (size_t)N_NODES * HID_DIM * 4;  // 8 MB
    float* zpre    = (float*)ws;                         ws += (size_t)N_NODES * Z_DIM * 4;    // 2 MB
    __hip_bfloat16* zb = (__hip_bfloat16*)ws;            ws += (size_t)N_NODES * Z_DIM * 2;    // 1 MB
    int* row_ptr   = (int*)ws;

    prep<<<PREP_SPLITX_BLOCKS + PREP_W1T_BLOCKS + PREP_ROWPTR_BLOCKS, 256, 0, stream>>>(
        x, xhi, xlo, w1, w1t_hi, w1t_lo, edge_row, row_ptr);

    gemm1_mfma<<<dim3(HID_DIM / 64, N_NODES / 128), 512, 0, stream>>>(
        xhi, xlo, w1t_hi, w1t_lo, support);

    spmm1_gemm2<<<N_NODES / 4, 256, 0, stream>>>(support, row_ptr, edge_col, edge_weight,
                                                 w2, zpre);

    spmm2<<<N_NODES / 4, 256, 0, stream>>>(zpre, row_ptr, edge_col, edge_weight, z_out, zb);

    recon_mfma<<<dim3(N_NODES / 128, N_NODES / 128), 256, 0, stream>>>(zb, recon);
}